// Round 1
// baseline (758.114 us; speedup 1.0000x reference)
//
#include <hip/hip_runtime.h>

#define RES    28
#define DIMC   384
#define NHEAD  8
#define HDIM   48
#define NPIX   784
#define NBATCH 16
#define SCALE  0.14433756729740643f  // 48^-0.5

// ================= fp32 tiled GEMM: out(M x 784) = W(M x 384) @ X[b](384 x 784) + bias ==========
// MODE 0: M=384, scatter to Q layout (b, h, n, d)
// MODE 1: M=768, rows <384 -> K natural (b, c, m); rows >=384 -> V layout (b, h, m, d)
// MODE 2: M=384, natural (b, c, n) (final output)
// BM=BN=64, BK=16, 256 threads, 4x4 micro-tile; all LDS compute reads are b128.
template <int MODE>
__global__ __launch_bounds__(256) void gemm_kernel(
    const float* __restrict__ W, const float* __restrict__ Wb,
    const float* __restrict__ X, float* __restrict__ out0, float* __restrict__ out1)
{
  __shared__ float sW[16][64];  // [k][m]
  __shared__ float sX[16][64];  // [k][n]

  const int t = threadIdx.x;
  const int tx = t & 15, ty = t >> 4;
  const int b = blockIdx.z;
  const int row0 = blockIdx.y * 64;
  const int n0 = blockIdx.x * 64;

  const float* Xb = X + (size_t)b * DIMC * NPIX;

  float acc[4][4];
#pragma unroll
  for (int i = 0; i < 4; ++i)
#pragma unroll
    for (int j = 0; j < 4; ++j) acc[i][j] = 0.f;

  const int wrow = t >> 2;          // 0..63
  const int wcol = (t & 3) << 2;    // 0,4,8,12
  const int xrow = t >> 4;          // 0..15
  const int xcol = (t & 15) << 2;   // 0..60
  const int nx = n0 + xcol;

  for (int k0 = 0; k0 < DIMC; k0 += 16) {
    // W tile: 64 rows x 16 k, coalesced float4, stored transposed [k][m]
    const float4 wv = *(const float4*)(W + (size_t)(row0 + wrow) * DIMC + k0 + wcol);
    sW[wcol + 0][wrow] = wv.x;
    sW[wcol + 1][wrow] = wv.y;
    sW[wcol + 2][wrow] = wv.z;
    sW[wcol + 3][wrow] = wv.w;
    // X tile: 16 k x 64 n  (784 % 4 == 0 so a float4 is all-in or all-out)
    float4 xv = make_float4(0.f, 0.f, 0.f, 0.f);
    if (nx < NPIX) xv = *(const float4*)(Xb + (size_t)(k0 + xrow) * NPIX + nx);
    *(float4*)&sX[xrow][xcol] = xv;
    __syncthreads();
#pragma unroll
    for (int k = 0; k < 16; ++k) {
      const float4 a4 = *(const float4*)&sW[k][ty << 2];
      const float4 b4 = *(const float4*)&sX[k][tx << 2];
      const float av[4] = {a4.x, a4.y, a4.z, a4.w};
      const float bv[4] = {b4.x, b4.y, b4.z, b4.w};
#pragma unroll
      for (int i = 0; i < 4; ++i)
#pragma unroll
        for (int j = 0; j < 4; ++j) acc[i][j] = fmaf(av[i], bv[j], acc[i][j]);
    }
    __syncthreads();
  }

#pragma unroll
  for (int i = 0; i < 4; ++i) {
    const int o = row0 + (ty << 2) + i;
    const float bias = Wb[o];
#pragma unroll
    for (int j = 0; j < 4; ++j) {
      const int n = n0 + (tx << 2) + j;
      if (n >= NPIX) continue;
      const float v = acc[i][j] + bias;
      if (MODE == 0) {
        const int hh = o / HDIM, d = o % HDIM;
        out0[(((size_t)b * NHEAD + hh) * NPIX + n) * HDIM + d] = v;
      } else if (MODE == 1) {
        if (o < DIMC) {
          out0[((size_t)b * DIMC + o) * NPIX + n] = v;          // K: (b, c, m)
        } else {
          const int o2 = o - DIMC;
          const int hh = o2 / HDIM, d = o2 % HDIM;
          out1[(((size_t)b * NHEAD + hh) * NPIX + n) * HDIM + d] = v;  // V: (b, h, m, d)
        }
      } else {
        out0[((size_t)b * DIMC + o) * NPIX + n] = v;
      }
    }
  }
}

// ================= attention: one block = (b, h, 16 query rows) ==========
// S (16x784 fp32) materialized in LDS; bias index computed analytically:
// bias_idxs[n][m] == |i1-i2|*28 + |j1-j2|  (offs dict filled by p1=(0,0) in row-major order)
__global__ __launch_bounds__(256) void attn_kernel(
    const float* __restrict__ Q, const float* __restrict__ K,
    const float* __restrict__ V, const float* __restrict__ biases,
    float* __restrict__ AO)
{
  __shared__ float sS[16][NPIX];   // 50176 B, reused as partial buffer at the end
  __shared__ float sQ[16][HDIM];   // [n][d]
  __shared__ float sBias[NPIX];    // attn_biases row for this head
  __shared__ float red[16][17];
  __shared__ float rowmax[16];
  __shared__ float rowinv[16];

  const int t = threadIdx.x;
  const int n0 = blockIdx.x * 16;
  const int h = blockIdx.y;
  const int b = blockIdx.z;

  // ---- stage Q tile (768 contiguous floats) + bias row ----
  const float* Qh = Q + (((size_t)b * NHEAD + h) * NPIX + n0) * HDIM;
  for (int idx = t; idx < 16 * HDIM; idx += 256) ((float*)sQ)[idx] = Qh[idx];
  for (int idx = t; idx < NPIX; idx += 256) sBias[idx] = biases[h * NPIX + idx];
  __syncthreads();

  // ---- S = scale * (Q K) + bias ; thread owns 4 m-columns (784 = 196*4) ----
  if (t < 196) {
    const int m0 = t << 2;
    const float* Kh = K + ((size_t)b * DIMC + h * HDIM) * NPIX + m0;
    float s[16][4];
#pragma unroll
    for (int n = 0; n < 16; ++n)
#pragma unroll
      for (int j = 0; j < 4; ++j) s[n][j] = 0.f;
    for (int dq = 0; dq < HDIM; dq += 4) {
      const float4 k0 = *(const float4*)(Kh + (size_t)(dq + 0) * NPIX);
      const float4 k1 = *(const float4*)(Kh + (size_t)(dq + 1) * NPIX);
      const float4 k2 = *(const float4*)(Kh + (size_t)(dq + 2) * NPIX);
      const float4 k3 = *(const float4*)(Kh + (size_t)(dq + 3) * NPIX);
      const float km[4][4] = {{k0.x, k0.y, k0.z, k0.w},
                              {k1.x, k1.y, k1.z, k1.w},
                              {k2.x, k2.y, k2.z, k2.w},
                              {k3.x, k3.y, k3.z, k3.w}};
#pragma unroll
      for (int n = 0; n < 16; ++n) {
        const float4 q4 = *(const float4*)&sQ[n][dq];
        const float qv[4] = {q4.x, q4.y, q4.z, q4.w};
#pragma unroll
        for (int r = 0; r < 4; ++r)
#pragma unroll
          for (int mm = 0; mm < 4; ++mm) s[n][mm] = fmaf(qv[r], km[r][mm], s[n][mm]);
      }
    }
#pragma unroll
    for (int n = 0; n < 16; ++n) {
      const int ng = n0 + n;
      const int i1 = ng / RES, j1 = ng % RES;
      float ov[4];
#pragma unroll
      for (int mm = 0; mm < 4; ++mm) {
        const int m = m0 + mm;
        const int i2 = m / RES, j2 = m % RES;
        const int di = (i1 > i2) ? (i1 - i2) : (i2 - i1);
        const int dj = (j1 > j2) ? (j1 - j2) : (j2 - j1);
        ov[mm] = fmaf(s[n][mm], SCALE, sBias[di * RES + dj]);
      }
      float4 o4; o4.x = ov[0]; o4.y = ov[1]; o4.z = ov[2]; o4.w = ov[3];
      *(float4*)&sS[n][m0] = o4;
    }
  }
  __syncthreads();

  // ---- softmax over m (rowwise), e-values left unnormalized in sS ----
  {
    const int row = t >> 4;
    const int g = t & 15;
    float pm = -1e30f;
    for (int mb = g << 2; mb < NPIX; mb += 64) {
      const float4 v = *(const float4*)&sS[row][mb];
      pm = fmaxf(pm, fmaxf(fmaxf(v.x, v.y), fmaxf(v.z, v.w)));
    }
    red[row][g] = pm;
    __syncthreads();
    if (t < 16) {
      float rm = red[t][0];
#pragma unroll
      for (int x = 1; x < 16; ++x) rm = fmaxf(rm, red[t][x]);
      rowmax[t] = rm;
    }
    __syncthreads();
    const float rm = rowmax[row];
    float ps = 0.f;
    for (int mb = g << 2; mb < NPIX; mb += 64) {
      float4 v = *(const float4*)&sS[row][mb];
      v.x = __expf(v.x - rm); v.y = __expf(v.y - rm);
      v.z = __expf(v.z - rm); v.w = __expf(v.w - rm);
      *(float4*)&sS[row][mb] = v;
      ps += v.x + v.y + v.z + v.w;
    }
    red[row][g] = ps;
    __syncthreads();
    if (t < 16) {
      float rs = 0.f;
#pragma unroll
      for (int x = 0; x < 16; ++x) rs += red[t][x];
      rowinv[t] = 1.f / rs;
    }
    __syncthreads();
  }

  // ---- O = P V : wave -> 4 rows; lane -> (msub m-quarter, dg d-quad); 4x4x4 blocks ----
  const int wv = t >> 6;
  const int lane = t & 63;
  const int dg = lane % 12;
  const int msub = lane / 12;    // lanes 48..63 idle
  float acc[4][4];
#pragma unroll
  for (int i = 0; i < 4; ++i)
#pragma unroll
    for (int j = 0; j < 4; ++j) acc[i][j] = 0.f;

  if (lane < 48) {
    const int nb = wv << 2;
    const float* Vh = V + ((size_t)b * NHEAD + h) * NPIX * HDIM + (dg << 2);
    const int mbeg = msub * 196;
    for (int m = mbeg; m < mbeg + 196; m += 4) {
      const float4 p0 = *(const float4*)&sS[nb + 0][m];
      const float4 p1 = *(const float4*)&sS[nb + 1][m];
      const float4 p2 = *(const float4*)&sS[nb + 2][m];
      const float4 p3 = *(const float4*)&sS[nb + 3][m];
      const float4 v0 = *(const float4*)(Vh + (size_t)(m + 0) * HDIM);
      const float4 v1 = *(const float4*)(Vh + (size_t)(m + 1) * HDIM);
      const float4 v2 = *(const float4*)(Vh + (size_t)(m + 2) * HDIM);
      const float4 v3 = *(const float4*)(Vh + (size_t)(m + 3) * HDIM);
      const float pr[4][4] = {{p0.x, p0.y, p0.z, p0.w}, {p1.x, p1.y, p1.z, p1.w},
                              {p2.x, p2.y, p2.z, p2.w}, {p3.x, p3.y, p3.z, p3.w}};
      const float vr[4][4] = {{v0.x, v0.y, v0.z, v0.w}, {v1.x, v1.y, v1.z, v1.w},
                              {v2.x, v2.y, v2.z, v2.w}, {v3.x, v3.y, v3.z, v3.w}};
#pragma unroll
      for (int ns = 0; ns < 4; ++ns)
#pragma unroll
        for (int mm = 0; mm < 4; ++mm)
#pragma unroll
          for (int dd = 0; dd < 4; ++dd)
            acc[ns][dd] = fmaf(pr[ns][mm], vr[mm][dd], acc[ns][dd]);
    }
  }
  __syncthreads();   // everyone done reading sS before we alias it

  float* part = &sS[0][0];   // [wv][msub][ns][HDIM] = 3072 floats, aliases sS
  if (lane < 48) {
#pragma unroll
    for (int ns = 0; ns < 4; ++ns)
#pragma unroll
      for (int dd = 0; dd < 4; ++dd)
        part[(((wv << 2) + msub) * 4 + ns) * HDIM + (dg << 2) + dd] = acc[ns][dd];
  }
  __syncthreads();

  // ---- reduce 4 m-quarters, normalize, scatter to attn_out (b, c, n) ----
  float* Oh = AO + ((size_t)b * DIMC + h * HDIM) * NPIX + n0;
  for (int idx = t; idx < 16 * HDIM; idx += 256) {
    const int n = idx & 15;
    const int d = idx >> 4;
    const int w2 = n >> 2, ns = n & 3;
    float sum = 0.f;
#pragma unroll
    for (int ms = 0; ms < 4; ++ms)
      sum += part[(((w2 << 2) + ms) * 4 + ns) * HDIM + d];
    Oh[(size_t)d * NPIX + n] = sum * rowinv[n];
  }
}

extern "C" void kernel_launch(void* const* d_in, const int* in_sizes, int n_in,
                              void* d_out, int out_size, void* d_ws, size_t ws_size,
                              hipStream_t stream)
{
  const float* ll     = (const float*)d_in[0];
  const float* ha     = (const float*)d_in[1];
  const float* q_w    = (const float*)d_in[2];
  const float* q_b    = (const float*)d_in[3];
  const float* kv_w   = (const float*)d_in[4];
  const float* kv_b   = (const float*)d_in[5];
  const float* proj_w = (const float*)d_in[6];
  const float* proj_b = (const float*)d_in[7];
  const float* biases = (const float*)d_in[8];
  // d_in[9] (bias_idxs) unused: index == |i1-i2|*28+|j1-j2| by construction
  float* out = (float*)d_out;

  const size_t plane = (size_t)NBATCH * DIMC * NPIX;
  float* Qb = (float*)d_ws;       // (b, h, n, d)
  float* Kb = Qb + plane;         // (b, c, m)
  float* Vb = Kb + plane;         // (b, h, m, d)
  float* AO = Vb + plane;         // (b, c, n)

  dim3 blk(256);
  hipLaunchKernelGGL((gemm_kernel<0>), dim3(13, 6, NBATCH), blk, 0, stream,
                     q_w, q_b, ll, Qb, (float*)nullptr);
  hipLaunchKernelGGL((gemm_kernel<1>), dim3(13, 12, NBATCH), blk, 0, stream,
                     kv_w, kv_b, ha, Kb, Vb);
  hipLaunchKernelGGL(attn_kernel, dim3(49, NHEAD, NBATCH), blk, 0, stream,
                     Qb, Kb, Vb, biases, AO);
  hipLaunchKernelGGL((gemm_kernel<2>), dim3(13, 6, NBATCH), blk, 0, stream,
                     proj_w, proj_b, AO, out, (float*)nullptr);
}

// Round 2
// 344.185 us; speedup vs baseline: 2.2026x; 2.2026x over previous
//
#include <hip/hip_runtime.h>

#define RES    28
#define DIMC   384
#define NHEAD  8
#define HDIM   48
#define DPAD   64
#define NPIX   784
#define NB     16
#define VSTR   800
#define PSTR   808
#define SCALE  0.14433756729740643f  // 48^-0.5

typedef short bf16x8 __attribute__((ext_vector_type(8)));
typedef float f32x4  __attribute__((ext_vector_type(4)));

__device__ __forceinline__ short f2bf(float x) {
  union { float f; unsigned u; } v; v.f = x;
  unsigned r = (v.u + 0x7FFFu + ((v.u >> 16) & 1u)) >> 16;  // RNE
  return (short)r;
}

// ========== pre-pass 1: transpose+convert X (b,c,pix) fp32 -> Xt (b,pix,c) bf16 ==========
__global__ __launch_bounds__(256) void transpose_cvt(
    const float* __restrict__ A, const float* __restrict__ Bt,
    short* __restrict__ TA, short* __restrict__ TB)
{
  __shared__ __align__(16) short sT[64][72];   // pad 72: aligned b128 reads, ~2-way banks
  const int t = threadIdx.x;
  const int which = blockIdx.z >> 4, b = blockIdx.z & 15;
  const float* X = (which ? Bt : A) + (size_t)b * DIMC * NPIX;
  short* T = (which ? TB : TA) + (size_t)b * NPIX * DIMC;
  const int c0 = blockIdx.y * 64, p0 = blockIdx.x * 64;
  const int rrr = t >> 4, pc = (t & 15) * 4;
#pragma unroll
  for (int i = 0; i < 4; ++i) {
    const int c = rrr + 16 * i;
    if (p0 + pc < NPIX) {     // 784%4==0: float4 all-in or all-out
      float4 v = *(const float4*)(X + (size_t)(c0 + c) * NPIX + p0 + pc);
      sT[pc + 0][c] = f2bf(v.x);
      sT[pc + 1][c] = f2bf(v.y);
      sT[pc + 2][c] = f2bf(v.z);
      sT[pc + 3][c] = f2bf(v.w);
    }
  }
  __syncthreads();
  const int pr = t >> 3, cc = (t & 7) * 8;
#pragma unroll
  for (int i = 0; i < 2; ++i) {
    const int p = pr + 32 * i;
    if (p0 + p < NPIX) {
      bf16x8 v = *(const bf16x8*)&sT[p][cc];
      *(bf16x8*)(T + (size_t)(p0 + p) * DIMC + c0 + cc) = v;
    }
  }
}

// ========== pre-pass 2: pack weights into MFMA A-fragment order (bf16) ==========
// Wf[mtile][kstep][lane][8] ; lane: row = mtile*16+(lane&15), k = kstep*32+(lane>>4)*8
__global__ __launch_bounds__(256) void pack_weights(
    const float* __restrict__ qw, const float* __restrict__ kvw, const float* __restrict__ pw,
    short* __restrict__ wfq, short* __restrict__ wfkv, short* __restrict__ wfp)
{
  int gid = blockIdx.x * 256 + threadIdx.x;   // 0..73727
  const float* W; short* O;
  if (gid < 18432)      { W = qw;  O = wfq; }
  else if (gid < 55296) { W = kvw; O = wfkv; gid -= 18432; }
  else                  { W = pw;  O = wfp;  gid -= 55296; }
  const int lane = gid & 63;
  const int kstep = (gid >> 6) % 12;
  const int mtile = gid / (64 * 12);
  const int row = mtile * 16 + (lane & 15);
  const int k = kstep * 32 + (lane >> 4) * 8;
  const float* src = W + (size_t)row * DIMC + k;
  const float4 a = *(const float4*)src;
  const float4 b = *(const float4*)(src + 4);
  bf16x8 o;
  o[0] = f2bf(a.x); o[1] = f2bf(a.y); o[2] = f2bf(a.z); o[3] = f2bf(a.w);
  o[4] = f2bf(b.x); o[5] = f2bf(b.y); o[6] = f2bf(b.z); o[7] = f2bf(b.w);
  *(bf16x8*)(O + (size_t)gid * 8) = o;
}

// ========== MFMA GEMM: C[b](M x 784) = W(M x 384) @ Xt[b]^T, no LDS ==========
// block=(n16, b), 4 waves; wave w owns mtiles {w, w+4, ...} (MT each).
// MODE 0: Q -> (b,h,pix,DPAD) bf16   MODE 1: K same / V -> (b,h,d,VSTR) bf16
// MODE 2: fp32 natural (b,c,pix)
template <int MT, int MODE>
__global__ __launch_bounds__(256) void mfma_gemm(
    const short* __restrict__ Wf, const float* __restrict__ Wb,
    const short* __restrict__ Xt, short* __restrict__ outA,
    short* __restrict__ outB, float* __restrict__ outF)
{
  const int t = threadIdx.x;
  const int w = t >> 6, lane = t & 63;
  const int rr = lane & 15, qq = lane >> 4;
  const int n16 = blockIdx.x, b = blockIdx.y;
  const int pix = n16 * 16 + rr;   // <= 783 always

  const short* Xp = Xt + ((size_t)b * NPIX + pix) * DIMC + qq * 8;

  f32x4 acc[MT];
#pragma unroll
  for (int i = 0; i < MT; ++i) acc[i] = (f32x4){0.f, 0.f, 0.f, 0.f};

  for (int ks = 0; ks < 12; ++ks) {
    const bf16x8 bf = *(const bf16x8*)(Xp + ks * 32);
#pragma unroll
    for (int i = 0; i < MT; ++i) {
      const int mtile = w + 4 * i;
      const bf16x8 af = *(const bf16x8*)(Wf + (((size_t)mtile * 12 + ks) * 64 + lane) * 8);
      acc[i] = __builtin_amdgcn_mfma_f32_16x16x32_bf16(af, bf, acc[i], 0, 0, 0);
    }
  }

#pragma unroll
  for (int i = 0; i < MT; ++i) {
    const int mtile = w + 4 * i;
    const int ch0 = mtile * 16 + qq * 4;        // 4 consecutive channels, never cross head
    const float4 bv = *(const float4*)(Wb + ch0);
    const float v0 = acc[i][0] + bv.x, v1 = acc[i][1] + bv.y;
    const float v2 = acc[i][2] + bv.z, v3 = acc[i][3] + bv.w;
    if (MODE == 2) {
      float* o = outF + ((size_t)b * DIMC + ch0) * NPIX + pix;
      o[0] = v0; o[NPIX] = v1; o[2 * NPIX] = v2; o[3 * NPIX] = v3;
    } else if (MODE == 0 || (MODE == 1 && ch0 < DIMC)) {     // Q or K: pixel-major, dpad 64
      const int hh = ch0 / HDIM, d0 = ch0 % HDIM;
      uint2 pk;
      pk.x = (unsigned short)f2bf(v0) | ((unsigned)(unsigned short)f2bf(v1) << 16);
      pk.y = (unsigned short)f2bf(v2) | ((unsigned)(unsigned short)f2bf(v3) << 16);
      *(uint2*)(outA + (((size_t)b * NHEAD + hh) * NPIX + pix) * DPAD + d0) = pk;
    } else {                                                  // V: (b,h,d,VSTR)
      const int ch2 = ch0 - DIMC;
      const int hh = ch2 / HDIM, d0 = ch2 % HDIM;
      short* o = outB + (((size_t)b * NHEAD + hh) * HDIM + d0) * VSTR + pix;
      o[0] = f2bf(v0); o[VSTR] = f2bf(v1); o[2 * VSTR] = f2bf(v2); o[3 * VSTR] = f2bf(v3);
    }
  }
}

// ========== attention: block = (qtile of 16 rows, h, b); S in registers ==========
__global__ __launch_bounds__(256) void attn_kernel(
    const short* __restrict__ Q, const short* __restrict__ K,
    const short* __restrict__ V, const float* __restrict__ biases,
    short* __restrict__ AO)
{
  __shared__ __align__(16) short sP[16 * PSTR];     // P bf16, A-frag readable
  __shared__ float sBias[NPIX];
  __shared__ float sOred[4 * 16 * HDIM];
  __shared__ float sRedM[4][16];
  __shared__ float sRedS[4][16];
  __shared__ float sRowinv[16];

  const int t = threadIdx.x;
  const int w = t >> 6, lane = t & 63;
  const int rr = lane & 15, qq = lane >> 4;
  const int qt = blockIdx.x, h = blockIdx.y, b = blockIdx.z;
  const int bh = b * NHEAD + h;
  const int qrow0 = qt * 16;

  for (int i = t; i < NPIX; i += 256) sBias[i] = biases[h * NPIX + i];

  // Q A-fragments (rows = qrow0 + (lane&15), k = d)
  const short* Qp = Q + ((size_t)bh * NPIX + qrow0 + rr) * DPAD + qq * 8;
  const bf16x8 qf0 = *(const bf16x8*)Qp;
  const bf16x8 qf1 = *(const bf16x8*)(Qp + 32);

  int i1[4], j1[4];
#pragma unroll
  for (int j = 0; j < 4; ++j) {
    const int qr = qrow0 + qq * 4 + j;
    i1[j] = qr / RES; j1[j] = qr - i1[j] * RES;
  }
  __syncthreads();

  // ---- phase 1: S = scale*(Q K^T) + bias, in registers (C-frag layout) ----
  f32x4 S[13];
  const short* Kb = K + (size_t)bh * NPIX * DPAD;
#pragma unroll
  for (int tt = 0; tt < 13; ++tt) {
    const int T = w + 4 * tt;
    if (T < 49) {
      const short* Kp = Kb + (size_t)(T * 16 + rr) * DPAD + qq * 8;
      const bf16x8 kf0 = *(const bf16x8*)Kp;
      const bf16x8 kf1 = *(const bf16x8*)(Kp + 32);
      f32x4 a = (f32x4){0.f, 0.f, 0.f, 0.f};
      a = __builtin_amdgcn_mfma_f32_16x16x32_bf16(qf0, kf0, a, 0, 0, 0);
      a = __builtin_amdgcn_mfma_f32_16x16x32_bf16(qf1, kf1, a, 0, 0, 0);
      const int kcol = T * 16 + rr;
      const int i2 = kcol / RES, j2 = kcol - (kcol / RES) * RES;
#pragma unroll
      for (int j = 0; j < 4; ++j) {
        int di = i1[j] - i2; di = di < 0 ? -di : di;
        int dj = j1[j] - j2; dj = dj < 0 ? -dj : dj;
        a[j] = fmaf(a[j], SCALE, sBias[di * RES + dj]);
      }
      S[tt] = a;
    }
  }

  // ---- row max: in-register -> 16-lane butterfly -> cross-wave via LDS ----
  float mx[4] = {-3e38f, -3e38f, -3e38f, -3e38f};
#pragma unroll
  for (int tt = 0; tt < 13; ++tt) {
    const int T = w + 4 * tt;
    if (T < 49) {
#pragma unroll
      for (int j = 0; j < 4; ++j) mx[j] = fmaxf(mx[j], S[tt][j]);
    }
  }
#pragma unroll
  for (int off = 1; off < 16; off <<= 1) {
#pragma unroll
    for (int j = 0; j < 4; ++j) mx[j] = fmaxf(mx[j], __shfl_xor(mx[j], off));
  }
  if (rr == 0) {
#pragma unroll
    for (int j = 0; j < 4; ++j) sRedM[w][qq * 4 + j] = mx[j];
  }
  __syncthreads();
  float m4[4];
#pragma unroll
  for (int j = 0; j < 4; ++j) {
    const int row = qq * 4 + j;
    m4[j] = fmaxf(fmaxf(sRedM[0][row], sRedM[1][row]), fmaxf(sRedM[2][row], sRedM[3][row]));
  }

  // ---- exp + row sum ----
  float sm[4] = {0.f, 0.f, 0.f, 0.f};
#pragma unroll
  for (int tt = 0; tt < 13; ++tt) {
    const int T = w + 4 * tt;
    if (T < 49) {
#pragma unroll
      for (int j = 0; j < 4; ++j) {
        const float p = __expf(S[tt][j] - m4[j]);
        S[tt][j] = p;
        sm[j] += p;
      }
    }
  }
#pragma unroll
  for (int off = 1; off < 16; off <<= 1) {
#pragma unroll
    for (int j = 0; j < 4; ++j) sm[j] += __shfl_xor(sm[j], off);
  }
  if (rr == 0) {
#pragma unroll
    for (int j = 0; j < 4; ++j) sRedS[w][qq * 4 + j] = sm[j];
  }
  __syncthreads();
  if (w == 0 && rr == 0) {
#pragma unroll
    for (int j = 0; j < 4; ++j) {
      const int row = qq * 4 + j;
      const float tot = sRedS[0][row] + sRedS[1][row] + sRedS[2][row] + sRedS[3][row];
      sRowinv[row] = 1.f / tot;
    }
  }

  // ---- write unnormalized P (bf16) to LDS + zero pad cols [784,800) ----
#pragma unroll
  for (int tt = 0; tt < 13; ++tt) {
    const int T = w + 4 * tt;
    if (T < 49) {
#pragma unroll
      for (int j = 0; j < 4; ++j)
        sP[(qq * 4 + j) * PSTR + T * 16 + rr] = f2bf(S[tt][j]);
    }
  }
  for (int i = t; i < 16 * 24; i += 256) {
    const int row = i / 24;
    sP[row * PSTR + NPIX + (i - row * 24)] = 0;
  }
  __syncthreads();

  // ---- phase 3: O = P V ; wave w owns ktiles {w, w+4, ...} < 25 ----
  f32x4 od[3];
#pragma unroll
  for (int dt = 0; dt < 3; ++dt) od[dt] = (f32x4){0.f, 0.f, 0.f, 0.f};
  const short* Vb = V + (size_t)bh * HDIM * VSTR;
#pragma unroll
  for (int tt = 0; tt < 7; ++tt) {
    const int kt = w + 4 * tt;
    if (kt < 25) {
      const bf16x8 pf = *(const bf16x8*)(sP + rr * PSTR + kt * 32 + qq * 8);
#pragma unroll
      for (int dt = 0; dt < 3; ++dt) {
        const bf16x8 vf = *(const bf16x8*)(Vb + (size_t)(dt * 16 + rr) * VSTR + kt * 32 + qq * 8);
        od[dt] = __builtin_amdgcn_mfma_f32_16x16x32_bf16(pf, vf, od[dt], 0, 0, 0);
      }
    }
  }
#pragma unroll
  for (int dt = 0; dt < 3; ++dt) {
#pragma unroll
    for (int j = 0; j < 4; ++j)
      sOred[(w * 16 + qq * 4 + j) * HDIM + dt * 16 + rr] = od[dt][j];
  }
  __syncthreads();

  // ---- reduce 4 waves, normalize, write AO (b,pix,384) bf16 ----
  for (int i = t; i < 16 * 24; i += 256) {
    const int row = i / 24;
    const int cp = (i - row * 24) * 2;
    float s0 = 0.f, s1 = 0.f;
#pragma unroll
    for (int w4 = 0; w4 < 4; ++w4) {
      s0 += sOred[(w4 * 16 + row) * HDIM + cp];
      s1 += sOred[(w4 * 16 + row) * HDIM + cp + 1];
    }
    const float riv = sRowinv[row];
    const unsigned pk = (unsigned short)f2bf(s0 * riv) |
                        ((unsigned)(unsigned short)f2bf(s1 * riv) << 16);
    *(unsigned*)(AO + ((size_t)b * NPIX + qrow0 + row) * DIMC + h * HDIM + cp) = pk;
  }
}

extern "C" void kernel_launch(void* const* d_in, const int* in_sizes, int n_in,
                              void* d_out, int out_size, void* d_ws, size_t ws_size,
                              hipStream_t stream)
{
  const float* ll     = (const float*)d_in[0];
  const float* ha     = (const float*)d_in[1];
  const float* q_w    = (const float*)d_in[2];
  const float* q_b    = (const float*)d_in[3];
  const float* kv_w   = (const float*)d_in[4];
  const float* kv_b   = (const float*)d_in[5];
  const float* proj_w = (const float*)d_in[6];
  const float* proj_b = (const float*)d_in[7];
  const float* biases = (const float*)d_in[8];
  // d_in[9] (bias_idxs) unused: index == |i1-i2|*28+|j1-j2| (validated in R1)
  float* out = (float*)d_out;

  short* Qb   = (short*)d_ws;                              // (b,h,784,64)
  short* Kb   = Qb  + (size_t)NB * NHEAD * NPIX * DPAD;    // (b,h,784,64)
  short* Vb   = Kb  + (size_t)NB * NHEAD * NPIX * DPAD;    // (b,h,48,800)
  short* Xll  = Vb  + (size_t)NB * NHEAD * HDIM * VSTR;    // (b,784,384)
  short* Xha  = Xll + (size_t)NB * NPIX * DIMC;
  short* AO   = Xha + (size_t)NB * NPIX * DIMC;            // (b,784,384)
  short* Wfq  = AO  + (size_t)NB * NPIX * DIMC;
  short* Wfkv = Wfq + (size_t)24 * 12 * 64 * 8;
  short* Wfp  = Wfkv + (size_t)48 * 12 * 64 * 8;

  // zero Q and K (covers the d in [48,64) pad columns)
  hipMemsetAsync(Qb, 0, (size_t)2 * NB * NHEAD * NPIX * DPAD * sizeof(short), stream);

  transpose_cvt<<<dim3(13, 6, 32), 256, 0, stream>>>(ll, ha, Xll, Xha);
  pack_weights<<<dim3(288), 256, 0, stream>>>(q_w, kv_w, proj_w, Wfq, Wfkv, Wfp);
  mfma_gemm<6, 0><<<dim3(49, NB), 256, 0, stream>>>(Wfq, q_b, Xll, Qb, nullptr, nullptr);
  mfma_gemm<12, 1><<<dim3(49, NB), 256, 0, stream>>>(Wfkv, kv_b, Xha, Kb, Vb, nullptr);
  attn_kernel<<<dim3(49, NHEAD, NB), 256, 0, stream>>>(Qb, Kb, Vb, biases, AO);
  mfma_gemm<6, 2><<<dim3(49, NB), 256, 0, stream>>>(Wfp, proj_b, AO, nullptr, nullptr, out);
}